// Round 1
// baseline (3685.616 us; speedup 1.0000x reference)
//
#include <hip/hip_runtime.h>
#include <hip/hip_bf16.h>

// HighSparsityMoE: x[2,1024,896] f32, 16 experts top-4 + shared expert, SwiGLU.
// Sparse dispatch (top-4 only) is numerically identical to reference dense dispatch
// (combine weight is exactly 0 for unselected experts).
//
// K1 router: 1 wave/token -> top4 lists per expert + P/f accumulators (ws)
// K2 loss finalize -> d_out[T*D]
// K3 fused FFN: block=(token-tile 64, group 0..16, I-chunk 256), 512 thr (8 waves)
//   GEMM1: G,U[64x256] = X*Wg|Wu   (mfma_f32_32x32x16_bf16, f32->bf16 on the fly)
//   GEMM2: O[64x896] += silu(G)*U @ Wd, O in regs, weighted atomicAdd to out.

#define T_TOK 2048
#define DIM   896
#define INTERN 2560
#define NEXP  16
#define TOPK  4
#define MT    64
#define IC    256
#define NCHUNK 10   // 2560/256

typedef __attribute__((ext_vector_type(8)))  __bf16 bf16x8;
typedef __attribute__((ext_vector_type(16))) float  f32x16;

__device__ __forceinline__ bf16x8 pack8(float4 a, float4 b) {
  bf16x8 r;
  r[0] = (__bf16)a.x; r[1] = (__bf16)a.y; r[2] = (__bf16)a.z; r[3] = (__bf16)a.w;
  r[4] = (__bf16)b.x; r[5] = (__bf16)b.y; r[6] = (__bf16)b.z; r[7] = (__bf16)b.w;
  return r;
}

// ---------------- K1: router ----------------
__global__ void router_k(const float* __restrict__ x, const float* __restrict__ rw,
                         int* __restrict__ cnt, float* __restrict__ Pacc,
                         float* __restrict__ facc, int* __restrict__ tok,
                         float* __restrict__ wts) {
  int lane = threadIdx.x & 63;
  int t = blockIdx.x * 4 + (threadIdx.x >> 6);
  const float* xr = x + (size_t)t * DIM;

  float acc[NEXP];
#pragma unroll
  for (int e = 0; e < NEXP; ++e) acc[e] = 0.f;
  for (int i = 0; i < DIM / 64; ++i) {
    int d = i * 64 + lane;
    float xv = xr[d];
    const float* r = rw + d * NEXP;
#pragma unroll
    for (int e = 0; e < NEXP; ++e) acc[e] = fmaf(xv, r[e], acc[e]);
  }
#pragma unroll
  for (int e = 0; e < NEXP; ++e) {
    float v = acc[e];
    v += __shfl_xor(v, 32); v += __shfl_xor(v, 16); v += __shfl_xor(v, 8);
    v += __shfl_xor(v, 4);  v += __shfl_xor(v, 2);  v += __shfl_xor(v, 1);
    acc[e] = v;
  }
  float m = acc[0];
#pragma unroll
  for (int e = 1; e < NEXP; ++e) m = fmaxf(m, acc[e]);
  float p[NEXP]; float s = 0.f;
#pragma unroll
  for (int e = 0; e < NEXP; ++e) { p[e] = __expf(acc[e] - m); s += p[e]; }
  float is = 1.f / s;
#pragma unroll
  for (int e = 0; e < NEXP; ++e) p[e] *= is;

  float pc[NEXP];
#pragma unroll
  for (int e = 0; e < NEXP; ++e) pc[e] = p[e];
  int sels[TOPK]; float svs[TOPK]; float s4 = 0.f;
#pragma unroll
  for (int k = 0; k < TOPK; ++k) {
    int best = 0; float bv = pc[0];
#pragma unroll
    for (int e = 1; e < NEXP; ++e) { if (pc[e] > bv) { bv = pc[e]; best = e; } }
    sels[k] = best; svs[k] = bv; s4 += bv;
#pragma unroll
    for (int e = 0; e < NEXP; ++e) { if (e == best) pc[e] = -1.f; }
  }
  float inv = 1.f / (s4 + 1e-8f);

  if (lane < NEXP) atomicAdd(&Pacc[lane], p[lane] * (1.f / T_TOK));
  if (lane < TOPK) {
    int e = sels[lane]; float w = svs[lane] * inv;
    atomicAdd(&facc[e], 1.f / T_TOK);
    int pos = atomicAdd(&cnt[e], 1);
    tok[e * T_TOK + pos] = t;
    wts[e * T_TOK + pos] = w;
  }
}

// ---------------- K2: balance loss ----------------
__global__ void loss_k(const float* __restrict__ Pacc, const float* __restrict__ facc,
                       float* __restrict__ dst) {
  if (threadIdx.x == 0) {
    float s = 0.f;
    for (int e = 0; e < NEXP; ++e) s += Pacc[e] * facc[e];
    *dst = (float)NEXP * s;
  }
}

// ---------------- K3: fused MoE FFN ----------------
__global__ __launch_bounds__(512, 2) void moe_k(
    const float* __restrict__ x, const int* __restrict__ cnt,
    const int* __restrict__ tok, const float* __restrict__ wts,
    const float* __restrict__ Wg, const float* __restrict__ Wu,
    const float* __restrict__ Wd, const float* __restrict__ Sg,
    const float* __restrict__ Su, const float* __restrict__ Sd,
    float* __restrict__ out) {
  int g = blockIdx.y, mt = blockIdx.x, ch = blockIdx.z;
  int M = (g < NEXP) ? cnt[g] : T_TOK;
  int m0 = mt * MT;
  if (m0 >= M) return;

  __shared__ int   rows_s[MT];
  __shared__ float w_s[MT];
  __shared__ __align__(16) __bf16 g_s[MT][136];  // pad 8: rows spread over banks
  __shared__ __align__(16) __bf16 u_s[MT][136];

  int tid = threadIdx.x;
  if (tid < MT) {
    if (g < NEXP) {
      int i = m0 + tid;
      bool v = i < M;
      rows_s[tid] = tok[g * T_TOK + (v ? i : m0)];
      w_s[tid]   = v ? wts[g * T_TOK + i] : 0.f;
    } else {
      rows_s[tid] = m0 + tid;
      w_s[tid]   = 1.f;
    }
  }
  __syncthreads();

  const float* pWg = (g < NEXP) ? Wg + (size_t)g * DIM * INTERN : Sg;
  const float* pWu = (g < NEXP) ? Wu + (size_t)g * DIM * INTERN : Su;
  const float* pWd = (g < NEXP) ? Wd + (size_t)g * INTERN * DIM : Sd;

  int wv = tid >> 6, lane = tid & 63;
  int h5 = lane >> 5, c31 = lane & 31;
  int mat = wv & 1, nfq = wv >> 1;            // GEMM1: wave = (G|U matrix, 32-col group)
  int mf2 = wv & 1, nb2 = (wv >> 1) * 7;      // GEMM2: wave = (token half, 7 of 28 col groups)
  int trow = mf2 * 32 + c31;

  int r0 = rows_s[c31], r1 = rows_s[32 + c31];
  const float* a0 = x + (size_t)r0 * DIM + 8 * h5;
  const float* a1 = x + (size_t)r1 * DIM + 8 * h5;
  const float* bp = mat ? pWu : pWg;
  int c0 = ch * IC;

  f32x16 oacc[7];
#pragma unroll
  for (int n = 0; n < 7; ++n)
#pragma unroll
    for (int r = 0; r < 16; ++r) oacc[n][r] = 0.f;

  for (int pass = 0; pass < 2; ++pass) {
    // ---- GEMM1: G|U[64x128] = X * W[:, pass slice], K=896 ----
    int ncol = c0 + pass * 128 + nfq * 32 + c31;
    const float* bb = bp + (size_t)(8 * h5) * INTERN + ncol;
    f32x16 acc0, acc1;
#pragma unroll
    for (int r = 0; r < 16; ++r) { acc0[r] = 0.f; acc1[r] = 0.f; }
    for (int ks = 0; ks < DIM / 16; ++ks) {
      const float4* ap0 = reinterpret_cast<const float4*>(a0 + ks * 16);
      const float4* ap1 = reinterpret_cast<const float4*>(a1 + ks * 16);
      bf16x8 af0 = pack8(ap0[0], ap0[1]);
      bf16x8 af1 = pack8(ap1[0], ap1[1]);
      const float* bk = bb + (size_t)ks * 16 * INTERN;
      bf16x8 bf;
#pragma unroll
      for (int e = 0; e < 8; ++e) bf[e] = (__bf16)bk[(size_t)e * INTERN];
      acc0 = __builtin_amdgcn_mfma_f32_32x32x16_bf16(af0, bf, acc0, 0, 0, 0);
      acc1 = __builtin_amdgcn_mfma_f32_32x32x16_bf16(af1, bf, acc1, 0, 0, 0);
    }
    // park G/U in LDS (bf16). C/D layout: col=lane&31, row=(r&3)+8*(r>>2)+4*(lane>>5)
    {
      __bf16 (*dst)[136] = mat ? u_s : g_s;
      int col = nfq * 32 + c31;
#pragma unroll
      for (int r = 0; r < 16; ++r) {
        int row = (r & 3) + 8 * (r >> 2) + 4 * h5;
        dst[row][col]      = (__bf16)acc0[r];
        dst[row + 32][col] = (__bf16)acc1[r];
      }
    }
    __syncthreads();

    // ---- GEMM2: O[64x896] += silu(G)*U @ Wd[pass slice, :], K=128 ----
    for (int kd = 0; kd < 8; ++kd) {
      int ic = kd * 16 + 8 * h5;
      bf16x8 gv = *reinterpret_cast<const bf16x8*>(&g_s[trow][ic]);
      bf16x8 uv = *reinterpret_cast<const bf16x8*>(&u_s[trow][ic]);
      bf16x8 hf;
#pragma unroll
      for (int e = 0; e < 8; ++e) {
        float gg = (float)gv[e], uu = (float)uv[e];
        hf[e] = (__bf16)(gg / (1.f + __expf(-gg)) * uu);
      }
      const float* bd = pWd + (size_t)(c0 + pass * 128 + kd * 16 + 8 * h5) * DIM;
#pragma unroll
      for (int nf = 0; nf < 7; ++nf) {
        int nc = (nb2 + nf) * 32 + c31;
        bf16x8 bfr;
#pragma unroll
        for (int e = 0; e < 8; ++e) bfr[e] = (__bf16)bd[(size_t)e * DIM + nc];
        oacc[nf] = __builtin_amdgcn_mfma_f32_32x32x16_bf16(hf, bfr, oacc[nf], 0, 0, 0);
      }
    }
    __syncthreads();
  }

  // epilogue: weighted scatter-add
#pragma unroll
  for (int nf = 0; nf < 7; ++nf) {
    int nc = (nb2 + nf) * 32 + c31;
#pragma unroll
    for (int r = 0; r < 16; ++r) {
      int row = (r & 3) + 8 * (r >> 2) + 4 * h5 + mf2 * 32;
      float v = oacc[nf][r] * w_s[row];
      atomicAdd(&out[(size_t)rows_s[row] * DIM + nc], v);
    }
  }
}

extern "C" void kernel_launch(void* const* d_in, const int* in_sizes, int n_in,
                              void* d_out, int out_size, void* d_ws, size_t ws_size,
                              hipStream_t stream) {
  const float* x  = (const float*)d_in[0];
  const float* rw = (const float*)d_in[1];
  const float* Wg = (const float*)d_in[2];
  const float* Wu = (const float*)d_in[3];
  const float* Wd = (const float*)d_in[4];
  const float* Sg = (const float*)d_in[5];
  const float* Su = (const float*)d_in[6];
  const float* Sd = (const float*)d_in[7];
  float* out = (float*)d_out;

  char* ws = (char*)d_ws;
  int*   cnt  = (int*)ws;                       // 16 ints
  float* Pacc = (float*)(ws + 64);              // 16 f32
  float* facc = (float*)(ws + 128);             // 16 f32
  int*   tok  = (int*)(ws + 256);               // 16*2048 ints
  float* wts  = (float*)(ws + 256 + sizeof(int) * NEXP * T_TOK);

  hipMemsetAsync(d_ws, 0, 256, stream);
  hipMemsetAsync(d_out, 0, (size_t)(T_TOK * DIM + 1) * sizeof(float), stream);

  router_k<<<T_TOK / 4, 256, 0, stream>>>(x, rw, cnt, Pacc, facc, tok, wts);
  loss_k<<<1, 64, 0, stream>>>(Pacc, facc, out + (size_t)T_TOK * DIM);
  dim3 grid(T_TOK / MT, NEXP + 1, NCHUNK);
  moe_k<<<grid, 512, 0, stream>>>(x, cnt, tok, wts, Wg, Wu, Wd, Sg, Su, Sd, out);
}

// Round 2
// 838.741 us; speedup vs baseline: 4.3942x; 4.3942x over previous
//
#include <hip/hip_runtime.h>
#include <hip/hip_bf16.h>

// HighSparsityMoE v2: x[2048,896] f32, 16 experts top-4 + shared, SwiGLU.
// K3: block = (64-token tile, group, one 256-wide I-chunk).
//   X staged once in LDS (bf16, XOR-swizzled). GEMM1 swapped-operand MFMA
//   -> H[64x256] bf16 in LDS -> GEMM2 with O[64x896] in regs -> atomic scatter.

#define T_TOK 2048
#define DIM   896
#define INTERN 2560
#define NEXP  16
#define TOPK  4
#define MT    64
#define IC    256

typedef __attribute__((ext_vector_type(8)))  __bf16 bf16x8;
typedef __attribute__((ext_vector_type(4)))  __bf16 bf16x4;
typedef __attribute__((ext_vector_type(16))) float  f32x16;

// ---------------- K1: router ----------------
__global__ void router_k(const float* __restrict__ x, const float* __restrict__ rw,
                         int* __restrict__ cnt, float* __restrict__ Pacc,
                         float* __restrict__ facc, int* __restrict__ tok,
                         float* __restrict__ wts) {
  int lane = threadIdx.x & 63;
  int t = blockIdx.x * 4 + (threadIdx.x >> 6);
  const float* xr = x + (size_t)t * DIM;

  float acc[NEXP];
#pragma unroll
  for (int e = 0; e < NEXP; ++e) acc[e] = 0.f;
  for (int i = 0; i < DIM / 64; ++i) {
    int d = i * 64 + lane;
    float xv = xr[d];
    const float* r = rw + d * NEXP;
#pragma unroll
    for (int e = 0; e < NEXP; ++e) acc[e] = fmaf(xv, r[e], acc[e]);
  }
#pragma unroll
  for (int e = 0; e < NEXP; ++e) {
    float v = acc[e];
    v += __shfl_xor(v, 32); v += __shfl_xor(v, 16); v += __shfl_xor(v, 8);
    v += __shfl_xor(v, 4);  v += __shfl_xor(v, 2);  v += __shfl_xor(v, 1);
    acc[e] = v;
  }
  float m = acc[0];
#pragma unroll
  for (int e = 1; e < NEXP; ++e) m = fmaxf(m, acc[e]);
  float p[NEXP]; float s = 0.f;
#pragma unroll
  for (int e = 0; e < NEXP; ++e) { p[e] = __expf(acc[e] - m); s += p[e]; }
  float is = 1.f / s;
#pragma unroll
  for (int e = 0; e < NEXP; ++e) p[e] *= is;

  float pc[NEXP];
#pragma unroll
  for (int e = 0; e < NEXP; ++e) pc[e] = p[e];
  int sels[TOPK]; float svs[TOPK]; float s4 = 0.f;
#pragma unroll
  for (int k = 0; k < TOPK; ++k) {
    int best = 0; float bv = pc[0];
#pragma unroll
    for (int e = 1; e < NEXP; ++e) { if (pc[e] > bv) { bv = pc[e]; best = e; } }
    sels[k] = best; svs[k] = bv; s4 += bv;
#pragma unroll
    for (int e = 0; e < NEXP; ++e) { if (e == best) pc[e] = -1.f; }
  }
  float inv = 1.f / (s4 + 1e-8f);

  if (lane < NEXP) atomicAdd(&Pacc[lane], p[lane] * (1.f / T_TOK));
  if (lane < TOPK) {
    int e = sels[lane]; float w = svs[lane] * inv;
    atomicAdd(&facc[e], 1.f / T_TOK);
    int pos = atomicAdd(&cnt[e], 1);
    tok[e * T_TOK + pos] = t;
    wts[e * T_TOK + pos] = w;
  }
}

// ---------------- K2: balance loss ----------------
__global__ void loss_k(const float* __restrict__ Pacc, const float* __restrict__ facc,
                       float* __restrict__ dst) {
  if (threadIdx.x == 0) {
    float s = 0.f;
    for (int e = 0; e < NEXP; ++e) s += Pacc[e] * facc[e];
    *dst = (float)NEXP * s;
  }
}

// ---------------- K3: fused MoE FFN v2 ----------------
__device__ __forceinline__ bf16x8 cvt8(const float* f) {
  bf16x8 r;
#pragma unroll
  for (int e = 0; e < 8; ++e) r[e] = (__bf16)f[e];
  return r;
}

__global__ __launch_bounds__(512, 2) void moe2_k(
    const float* __restrict__ x, const int* __restrict__ cnt,
    const int* __restrict__ tok, const float* __restrict__ wts,
    const float* __restrict__ Wg, const float* __restrict__ Wu,
    const float* __restrict__ Wd, const float* __restrict__ Sg,
    const float* __restrict__ Su, const float* __restrict__ Sd,
    float* __restrict__ out) {
  // XCD-aware bid decode: expert e's blocks all have bid % 8 == (e&7).
  int bid = blockIdx.x;
  int g, tile, ch;
  if (bid < 5120) {
    g = (bid & 7) + 8 * ((bid >> 3) & 1);
    tile = (bid >> 4) & 31;
    ch = bid >> 9;
  } else {
    int s = bid - 5120;
    int q = s >> 3;
    ch = q % 10;
    tile = (s & 7) + 8 * (q / 10);
    g = NEXP;
  }
  int M = (g < NEXP) ? cnt[g] : T_TOK;
  int m0 = tile * MT;
  if (m0 >= M) return;

  __shared__ int rows_s[MT];
  __shared__ float w_s[MT];
  __shared__ __align__(16) char xbuf[MT * DIM * 2];   // 112 KiB swizzled bf16
  __shared__ __align__(16) char hbuf[MT * IC * 2];    // 32 KiB swizzled bf16

  int tid = threadIdx.x;
  if (tid < MT) {
    if (g < NEXP) {
      int i = m0 + tid;
      bool v = i < M;
      rows_s[tid] = tok[g * T_TOK + (v ? i : m0)];
      w_s[tid]   = v ? wts[g * T_TOK + i] : 0.f;
    } else {
      rows_s[tid] = m0 + tid;
      w_s[tid]   = 1.f;
    }
  }
  __syncthreads();

  // ---- stage gathered X tile -> LDS bf16, swizzle byte ^= (row&7)<<4 ----
  {
    int r = tid >> 3, c8 = tid & 7;
    const float* xr = x + (size_t)rows_s[r] * DIM;
#pragma unroll
    for (int j = 0; j < 28; ++j) {
      int c4 = c8 + 8 * j;                       // float4 index, 0..223
      float4 v = reinterpret_cast<const float4*>(xr)[c4];
      bf16x4 b;
      b[0] = (__bf16)v.x; b[1] = (__bf16)v.y; b[2] = (__bf16)v.z; b[3] = (__bf16)v.w;
      int byte = r * (DIM * 2) + c4 * 8;
      byte ^= (r & 7) << 4;
      *reinterpret_cast<bf16x4*>(xbuf + byte) = b;
    }
  }
  __syncthreads();

  const float* pWg = (g < NEXP) ? Wg + (size_t)g * DIM * INTERN : Sg;
  const float* pWu = (g < NEXP) ? Wu + (size_t)g * DIM * INTERN : Su;
  const float* pWd = (g < NEXP) ? Wd + (size_t)g * INTERN * DIM : Sd;

  int wv = tid >> 6, lane = tid & 63;
  int h5 = lane >> 5, c31 = lane & 31;
  int c0 = ch * IC;

  // ---- GEMM1 (swapped): D'[i][tok] = W^T-frag x X-frag, K=896 ----
  // wave wv owns I-window [c0+wv*32, +32), both token halves, G and U.
  f32x16 ag0, ag1, au0, au1;
#pragma unroll
  for (int r = 0; r < 16; ++r) { ag0[r] = 0.f; ag1[r] = 0.f; au0[r] = 0.f; au1[r] = 0.f; }

  const float* bg = pWg + (size_t)(8 * h5) * INTERN + c0 + wv * 32 + c31;
  const float* bu = pWu + (size_t)(8 * h5) * INTERN + c0 + wv * 32 + c31;

  float fg0[8], fu0[8], fg1[8], fu1[8];
#pragma unroll
  for (int e = 0; e < 8; ++e) {
    fg0[e] = bg[(size_t)e * INTERN];
    fu0[e] = bu[(size_t)e * INTERN];
  }

#define XFRAG(tokrow, ks) \
  (*reinterpret_cast<const bf16x8*>(xbuf + (((tokrow) * (DIM * 2) + (ks) * 32 + h5 * 16) ^ (((tokrow) & 7) << 4))))

  for (int ks2 = 0; ks2 < 28; ++ks2) {
    int ksA = 2 * ks2, ksB = ksA + 1;
    const float* bgB = bg + (size_t)ksB * 16 * INTERN;
    const float* buB = bu + (size_t)ksB * 16 * INTERN;
#pragma unroll
    for (int e = 0; e < 8; ++e) {
      fg1[e] = bgB[(size_t)e * INTERN];
      fu1[e] = buB[(size_t)e * INTERN];
    }
    {
      bf16x8 xa = XFRAG(c31, ksA), xb = XFRAG(c31 + 32, ksA);
      bf16x8 wgf = cvt8(fg0), wuf = cvt8(fu0);
      ag0 = __builtin_amdgcn_mfma_f32_32x32x16_bf16(wgf, xa, ag0, 0, 0, 0);
      ag1 = __builtin_amdgcn_mfma_f32_32x32x16_bf16(wgf, xb, ag1, 0, 0, 0);
      au0 = __builtin_amdgcn_mfma_f32_32x32x16_bf16(wuf, xa, au0, 0, 0, 0);
      au1 = __builtin_amdgcn_mfma_f32_32x32x16_bf16(wuf, xb, au1, 0, 0, 0);
    }
    const float* bgC = (ks2 < 27) ? bg + (size_t)(ksA + 2) * 16 * INTERN : bg;
    const float* buC = (ks2 < 27) ? bu + (size_t)(ksA + 2) * 16 * INTERN : bu;
#pragma unroll
    for (int e = 0; e < 8; ++e) {
      fg0[e] = bgC[(size_t)e * INTERN];
      fu0[e] = buC[(size_t)e * INTERN];
    }
    {
      bf16x8 xa = XFRAG(c31, ksB), xb = XFRAG(c31 + 32, ksB);
      bf16x8 wgf = cvt8(fg1), wuf = cvt8(fu1);
      ag0 = __builtin_amdgcn_mfma_f32_32x32x16_bf16(wgf, xa, ag0, 0, 0, 0);
      ag1 = __builtin_amdgcn_mfma_f32_32x32x16_bf16(wgf, xb, ag1, 0, 0, 0);
      au0 = __builtin_amdgcn_mfma_f32_32x32x16_bf16(wuf, xa, au0, 0, 0, 0);
      au1 = __builtin_amdgcn_mfma_f32_32x32x16_bf16(wuf, xb, au1, 0, 0, 0);
    }
  }

  // ---- SwiGLU in-register, H -> LDS (row-major [tok][IC], swizzled) ----
#pragma unroll
  for (int mh = 0; mh < 2; ++mh) {
    int tokr = c31 + 32 * mh;
#pragma unroll
    for (int q = 0; q < 4; ++q) {
      bf16x4 hq;
#pragma unroll
      for (int j = 0; j < 4; ++j) {
        float gg = mh ? ag1[4 * q + j] : ag0[4 * q + j];
        float uu = mh ? au1[4 * q + j] : au0[4 * q + j];
        hq[j] = (__bf16)(gg / (1.f + __expf(-gg)) * uu);
      }
      int i0 = wv * 32 + 8 * q + 4 * h5;
      int byte = tokr * (IC * 2) + i0 * 2;
      byte ^= (tokr & 7) << 4;
      *reinterpret_cast<bf16x4*>(hbuf + byte) = hq;
    }
  }
  __syncthreads();

  // ---- GEMM2: O[64x896] = H @ Wd[chunk], K=256; O in regs ----
  int mh = wv & 1;
  int ngb = (wv >> 1) * 7;           // 7 n-groups of 32 cols
  int tokr = c31 + 32 * mh;
  f32x16 o[7];
#pragma unroll
  for (int n = 0; n < 7; ++n)
#pragma unroll
    for (int r = 0; r < 16; ++r) o[n][r] = 0.f;

  const float* bd = pWd + (size_t)(c0 + 8 * h5) * DIM + ngb * 32 + c31;

  float fA[8], fB[8];
#pragma unroll
  for (int e = 0; e < 8; ++e) fA[e] = bd[(size_t)e * DIM];   // (ks0, nf0)

  auto g2body = [&](int ks, auto P) {
    constexpr int par = decltype(P)::value;   // ks & 1, compile-time
    int hbyte = (tokr * (IC * 2) + ks * 32 + h5 * 16) ^ ((tokr & 7) << 4);
    bf16x8 hf = *reinterpret_cast<const bf16x8*>(hbuf + hbyte);
    const float* bk  = bd + (size_t)(ks * 16) * DIM;
    const float* bk1 = bd + (size_t)(((ks < 15) ? (ks + 1) : ks) * 16) * DIM;
#pragma unroll
    for (int nf = 0; nf < 7; ++nf) {
      // consumption index n = ks*7+nf; buffer = (ks+nf)&1 (7 odd)
      float* nxt = (((nf + par) & 1) == 0) ? fB : fA;
      const float* src = (nf < 6) ? (bk + (nf + 1) * 32) : bk1;
#pragma unroll
      for (int e = 0; e < 8; ++e) nxt[e] = src[(size_t)e * DIM];
      const float* cur = (((nf + par) & 1) == 0) ? fA : fB;
      bf16x8 bfr = cvt8(cur);
      o[nf] = __builtin_amdgcn_mfma_f32_32x32x16_bf16(hf, bfr, o[nf], 0, 0, 0);
    }
  };
  for (int k2 = 0; k2 < 8; ++k2) {
    g2body(2 * k2,     std::integral_constant<int, 0>{});
    g2body(2 * k2 + 1, std::integral_constant<int, 1>{});
  }

  // ---- epilogue: weighted scatter-add ----
#pragma unroll
  for (int nf = 0; nf < 7; ++nf) {
    int nc = (ngb + nf) * 32 + c31;
#pragma unroll
    for (int r = 0; r < 16; ++r) {
      int row = (r & 3) + 8 * (r >> 2) + 4 * h5 + 32 * mh;
      atomicAdd(&out[(size_t)rows_s[row] * DIM + nc], o[nf][r] * w_s[row]);
    }
  }
}

extern "C" void kernel_launch(void* const* d_in, const int* in_sizes, int n_in,
                              void* d_out, int out_size, void* d_ws, size_t ws_size,
                              hipStream_t stream) {
  const float* x  = (const float*)d_in[0];
  const float* rw = (const float*)d_in[1];
  const float* Wg = (const float*)d_in[2];
  const float* Wu = (const float*)d_in[3];
  const float* Wd = (const float*)d_in[4];
  const float* Sg = (const float*)d_in[5];
  const float* Su = (const float*)d_in[6];
  const float* Sd = (const float*)d_in[7];
  float* out = (float*)d_out;

  char* ws = (char*)d_ws;
  int*   cnt  = (int*)ws;                       // 16 ints
  float* Pacc = (float*)(ws + 64);              // 16 f32
  float* facc = (float*)(ws + 128);             // 16 f32
  int*   tok  = (int*)(ws + 256);               // 16*2048 ints
  float* wts  = (float*)(ws + 256 + sizeof(int) * NEXP * T_TOK);

  hipMemsetAsync(d_ws, 0, 256, stream);
  hipMemsetAsync(d_out, 0, (size_t)(T_TOK * DIM + 1) * sizeof(float), stream);

  router_k<<<T_TOK / 4, 256, 0, stream>>>(x, rw, cnt, Pacc, facc, tok, wts);
  loss_k<<<1, 64, 0, stream>>>(Pacc, facc, out + (size_t)T_TOK * DIM);
  moe2_k<<<5440, 512, 0, stream>>>(x, cnt, tok, wts, Wg, Wu, Wd, Sg, Su, Sd, out);
}

// Round 4
// 699.253 us; speedup vs baseline: 5.2708x; 1.1995x over previous
//
#include <hip/hip_runtime.h>
#include <hip/hip_bf16.h>
#include <type_traits>

// HighSparsityMoE v3.1: two-stage MoE FFN.
//  h_k  (g,tile,ch): GEMM1+SwiGLU -> H[slot][2560] bf16 in ws (2 blocks/CU)
//  g2_k (g,tile,ns): GEMM2 K=2560, 128 cols/block, O=16 regs
// v3.1 fix: h_k tail tiles must NOT store rows >= M (slots are prefix-packed;
// storing them corrupts the NEXT expert's H rows — the r3 absmax 2.13 bug).
// Fallback to v2 single-kernel (moe2_k) if ws_size too small for H.

#define T_TOK 2048
#define DIM   896
#define INTERN 2560
#define NEXP  16
#define TOPK  4
#define MT    64
#define IC    256

typedef __attribute__((ext_vector_type(8)))  __bf16 bf16x8;
typedef __attribute__((ext_vector_type(4)))  __bf16 bf16x4;
typedef __attribute__((ext_vector_type(16))) float  f32x16;

__device__ __forceinline__ bf16x8 cvt8(const float* f) {
  bf16x8 r;
#pragma unroll
  for (int e = 0; e < 8; ++e) r[e] = (__bf16)f[e];
  return r;
}
__device__ __forceinline__ void ldw8i(float b[8], const float* p) {
#pragma unroll
  for (int e = 0; e < 8; ++e) b[e] = p[(size_t)e * INTERN];
}
__device__ __forceinline__ void ldw8d(float b[8], const float* p) {
#pragma unroll
  for (int e = 0; e < 8; ++e) b[e] = p[(size_t)e * DIM];
}
// barrier that does NOT drain vmcnt (keeps global prefetch in flight)
__device__ __forceinline__ void panel_barrier() {
  asm volatile("s_waitcnt lgkmcnt(0)" ::: "memory");
  __builtin_amdgcn_s_barrier();
  __builtin_amdgcn_sched_barrier(0);
}

// ---------------- K1: router ----------------
__global__ void router_k(const float* __restrict__ x, const float* __restrict__ rw,
                         int* __restrict__ cnt, float* __restrict__ Pacc,
                         float* __restrict__ facc, int* __restrict__ tok,
                         float* __restrict__ wts) {
  int lane = threadIdx.x & 63;
  int t = blockIdx.x * 4 + (threadIdx.x >> 6);
  const float* xr = x + (size_t)t * DIM;

  float acc[NEXP];
#pragma unroll
  for (int e = 0; e < NEXP; ++e) acc[e] = 0.f;
  for (int i = 0; i < DIM / 64; ++i) {
    int d = i * 64 + lane;
    float xv = xr[d];
    const float* r = rw + d * NEXP;
#pragma unroll
    for (int e = 0; e < NEXP; ++e) acc[e] = fmaf(xv, r[e], acc[e]);
  }
#pragma unroll
  for (int e = 0; e < NEXP; ++e) {
    float v = acc[e];
    v += __shfl_xor(v, 32); v += __shfl_xor(v, 16); v += __shfl_xor(v, 8);
    v += __shfl_xor(v, 4);  v += __shfl_xor(v, 2);  v += __shfl_xor(v, 1);
    acc[e] = v;
  }
  float m = acc[0];
#pragma unroll
  for (int e = 1; e < NEXP; ++e) m = fmaxf(m, acc[e]);
  float p[NEXP]; float s = 0.f;
#pragma unroll
  for (int e = 0; e < NEXP; ++e) { p[e] = __expf(acc[e] - m); s += p[e]; }
  float is = 1.f / s;
#pragma unroll
  for (int e = 0; e < NEXP; ++e) p[e] *= is;

  float pc[NEXP];
#pragma unroll
  for (int e = 0; e < NEXP; ++e) pc[e] = p[e];
  int sels[TOPK]; float svs[TOPK]; float s4 = 0.f;
#pragma unroll
  for (int k = 0; k < TOPK; ++k) {
    int best = 0; float bv = pc[0];
#pragma unroll
    for (int e = 1; e < NEXP; ++e) { if (pc[e] > bv) { bv = pc[e]; best = e; } }
    sels[k] = best; svs[k] = bv; s4 += bv;
#pragma unroll
    for (int e = 0; e < NEXP; ++e) { if (e == best) pc[e] = -1.f; }
  }
  float inv = 1.f / (s4 + 1e-8f);

  if (lane < NEXP) atomicAdd(&Pacc[lane], p[lane] * (1.f / T_TOK));
  if (lane < TOPK) {
    int e = sels[lane]; float w = svs[lane] * inv;
    atomicAdd(&facc[e], 1.f / T_TOK);
    int pos = atomicAdd(&cnt[e], 1);
    tok[e * T_TOK + pos] = t;
    wts[e * T_TOK + pos] = w;
  }
}

// ---------------- K2: balance loss + expert offsets ----------------
__global__ void loss_k(const float* __restrict__ Pacc, const float* __restrict__ facc,
                       const int* __restrict__ cnt, int* __restrict__ offs,
                       float* __restrict__ dst) {
  if (threadIdx.x == 0) {
    float s = 0.f;
    for (int e = 0; e < NEXP; ++e) s += Pacc[e] * facc[e];
    *dst = (float)NEXP * s;
    int o = 0;
    for (int e = 0; e < NEXP; ++e) { offs[e] = o; o += cnt[e]; }
    offs[NEXP] = o;   // = 8192 (shared base)
  }
}

// ---------------- K3a: h_k — GEMM1 + SwiGLU -> H ----------------
__global__ __launch_bounds__(512, 4) void h_k(
    const float* __restrict__ x, const int* __restrict__ cnt,
    const int* __restrict__ offs, const int* __restrict__ tok,
    const float* __restrict__ Wg, const float* __restrict__ Wu,
    const float* __restrict__ Sg, const float* __restrict__ Su,
    __hip_bfloat16* __restrict__ H) {
  int bid = blockIdx.x;
  int g, tile, ch;
  if (bid < 5120) {                      // routed: bid%8 == g&7 (XCD affinity)
    g = (bid & 7) + 8 * ((bid >> 3) & 1);
    tile = (bid >> 4) & 31;
    ch = bid >> 9;
  } else {                               // shared: bid%8 == tile&7
    int s = bid - 5120;
    tile = s & 31;
    ch = s >> 5;
    g = NEXP;
  }
  int M = (g < NEXP) ? cnt[g] : T_TOK;
  int m0 = tile * MT;
  if (m0 >= M) return;

  __shared__ int rows_s[MT];
  __shared__ __align__(16) char xp[2][16384];   // [64][128] bf16, swizzled
  __shared__ __align__(16) char hb[MT * IC * 2];

  int tid = threadIdx.x;
  if (tid < MT) {
    if (g < NEXP) {
      int i = m0 + tid;
      rows_s[tid] = tok[g * T_TOK + ((i < M) ? i : m0)];
    } else rows_s[tid] = m0 + tid;
  }
  __syncthreads();

  const float* pWg = (g < NEXP) ? Wg + (size_t)g * DIM * INTERN : Sg;
  const float* pWu = (g < NEXP) ? Wu + (size_t)g * DIM * INTERN : Su;

  int wv = tid >> 6, lane = tid & 63;
  int h5 = lane >> 5, c31 = lane & 31;
  int c0 = ch * IC;

  // staging ids: thread = (row, 1/8 of row)
  int srow = tid >> 3, sc8 = tid & 7;
  const float* xr = x + (size_t)rows_s[srow] * DIM;
  int sswz = (srow & 7) << 4;

#define LDX(p, j) (*reinterpret_cast<const float4*>(xr + (p) * 128 + (sc8 + 8 * (j)) * 4))
#define STX(pb, j, v) { bf16x4 _b; _b[0]=(__bf16)(v).x; _b[1]=(__bf16)(v).y; \
    _b[2]=(__bf16)(v).z; _b[3]=(__bf16)(v).w; \
    *reinterpret_cast<bf16x4*>(&xp[pb][(srow * 256 + sc8 * 8 + 64 * (j)) ^ sswz]) = _b; }
#define XF(pb, row, ksl) (*reinterpret_cast<const bf16x8*>( \
    &xp[pb][((row) * 256 + (ksl) * 32 + h5 * 16) ^ (((row) & 7) << 4)]))

  const float* bg = pWg + (size_t)(8 * h5) * INTERN + c0 + wv * 32 + c31;
  const float* bu = pWu + (size_t)(8 * h5) * INTERN + c0 + wv * 32 + c31;

  float fg0[8], fu0[8], fg1[8], fu1[8];
  ldw8i(fg0, bg); ldw8i(fu0, bu);        // ks = 0

  // prologue: stage panel 0
  {
    float4 a0 = LDX(0, 0), a1 = LDX(0, 1), a2 = LDX(0, 2), a3 = LDX(0, 3);
    STX(0, 0, a0) STX(0, 1, a1) STX(0, 2, a2) STX(0, 3, a3)
  }
  panel_barrier();

  f32x16 ag0, ag1, au0, au1;
#pragma unroll
  for (int r = 0; r < 16; ++r) { ag0[r] = 0.f; ag1[r] = 0.f; au0[r] = 0.f; au1[r] = 0.f; }

  float4 s0, s1, s2, s3;
  for (int p = 0; p < 7; ++p) {
    int pb = p & 1;
    if (p < 6) { s0 = LDX(p + 1, 0); s1 = LDX(p + 1, 1); }
#pragma unroll
    for (int q = 0; q < 4; ++q) {
      int ksA = 8 * p + 2 * q, ksB = ksA + 1;
      ldw8i(fg1, bg + (size_t)ksB * 16 * INTERN);
      ldw8i(fu1, bu + (size_t)ksB * 16 * INTERN);
      {
        bf16x8 xa = XF(pb, c31, 2 * q), xb = XF(pb, c31 + 32, 2 * q);
        bf16x8 wgf = cvt8(fg0), wuf = cvt8(fu0);
        ag0 = __builtin_amdgcn_mfma_f32_32x32x16_bf16(wgf, xa, ag0, 0, 0, 0);
        ag1 = __builtin_amdgcn_mfma_f32_32x32x16_bf16(wgf, xb, ag1, 0, 0, 0);
        au0 = __builtin_amdgcn_mfma_f32_32x32x16_bf16(wuf, xa, au0, 0, 0, 0);
        au1 = __builtin_amdgcn_mfma_f32_32x32x16_bf16(wuf, xb, au1, 0, 0, 0);
      }
      int ksC = (ksA + 2 < 56) ? (ksA + 2) : 0;
      ldw8i(fg0, bg + (size_t)ksC * 16 * INTERN);
      ldw8i(fu0, bu + (size_t)ksC * 16 * INTERN);
      {
        bf16x8 xa = XF(pb, c31, 2 * q + 1), xb = XF(pb, c31 + 32, 2 * q + 1);
        bf16x8 wgf = cvt8(fg1), wuf = cvt8(fu1);
        ag0 = __builtin_amdgcn_mfma_f32_32x32x16_bf16(wgf, xa, ag0, 0, 0, 0);
        ag1 = __builtin_amdgcn_mfma_f32_32x32x16_bf16(wgf, xb, ag1, 0, 0, 0);
        au0 = __builtin_amdgcn_mfma_f32_32x32x16_bf16(wuf, xa, au0, 0, 0, 0);
        au1 = __builtin_amdgcn_mfma_f32_32x32x16_bf16(wuf, xb, au1, 0, 0, 0);
      }
      if (q == 1 && p < 6) {
        STX(pb ^ 1, 0, s0) STX(pb ^ 1, 1, s1)
        s2 = LDX(p + 1, 2); s3 = LDX(p + 1, 3);
      }
    }
    if (p < 6) { STX(pb ^ 1, 2, s2) STX(pb ^ 1, 3, s3) }
    panel_barrier();
  }

  // SwiGLU in-register -> hb ([tok][256] bf16, swizzled)
#pragma unroll
  for (int mh = 0; mh < 2; ++mh) {
    int tokr = c31 + 32 * mh;
#pragma unroll
    for (int q = 0; q < 4; ++q) {
      bf16x4 hq;
#pragma unroll
      for (int j = 0; j < 4; ++j) {
        float gg = mh ? ag1[4 * q + j] : ag0[4 * q + j];
        float uu = mh ? au1[4 * q + j] : au0[4 * q + j];
        hq[j] = (__bf16)(gg / (1.f + __expf(-gg)) * uu);
      }
      int i0 = wv * 32 + 8 * q + 4 * h5;
      int byte = (tokr * 512 + i0 * 2) ^ ((tokr & 7) << 4);
      *reinterpret_cast<bf16x4*>(&hb[byte]) = hq;
    }
  }
  panel_barrier();

  // wide store hb -> H[slot][c0..c0+256)  — ONLY for valid rows (v3.1 fix):
  // tail rows >= M would land in the NEXT expert's packed slots.
  if (g == NEXP || m0 + srow < M) {
    int slot = offs[g] + m0 + srow;
    __hip_bfloat16* hrow = H + (size_t)slot * INTERN + c0 + sc8 * 32;
#pragma unroll
    for (int qq = 0; qq < 4; ++qq) {
      int byte = (srow * 512 + sc8 * 64 + qq * 16) ^ sswz;
      *reinterpret_cast<bf16x8*>(hrow + qq * 8) =
          *reinterpret_cast<const bf16x8*>(&hb[byte]);
    }
  }
#undef LDX
#undef STX
#undef XF
}

// ---------------- K3b: g2_k — O = H @ Wd (K=2560), weighted scatter ----------------
__global__ __launch_bounds__(512, 4) void g2_k(
    const int* __restrict__ cnt, const int* __restrict__ offs,
    const int* __restrict__ tok, const float* __restrict__ wts,
    const __hip_bfloat16* __restrict__ H,
    const float* __restrict__ Wd, const float* __restrict__ Sd,
    float* __restrict__ out) {
  int bid = blockIdx.x;
  int g, tile, ns;
  if (bid < 3584) {
    g = (bid & 7) + 8 * ((bid >> 3) & 1);
    tile = (bid >> 4) & 31;
    ns = bid >> 9;                       // 0..6
  } else {
    int s = bid - 3584;
    tile = s & 31;
    ns = s >> 5;
    g = NEXP;
  }
  int M = (g < NEXP) ? cnt[g] : T_TOK;
  int m0 = tile * MT;
  if (m0 >= M) return;

  __shared__ int rows_s[MT];
  __shared__ float w_s[MT];
  __shared__ __align__(16) char hp[2][16384];   // [64][128] bf16, swizzled

  int tid = threadIdx.x;
  if (tid < MT) {
    if (g < NEXP) {
      int i = m0 + tid; bool v = i < M;
      rows_s[tid] = tok[g * T_TOK + (v ? i : m0)];
      w_s[tid]   = v ? wts[g * T_TOK + i] : 0.f;
    } else { rows_s[tid] = m0 + tid; w_s[tid] = 1.f; }
  }
  __syncthreads();

  const float* pWd = (g < NEXP) ? Wd + (size_t)g * INTERN * DIM : Sd;
  int wv = tid >> 6, lane = tid & 63, h5 = lane >> 5, c31 = lane & 31;
  int mh = wv & 1, ng = wv >> 1;
  int col = ns * 128 + ng * 32 + c31;
  const float* bd = pWd + (size_t)(8 * h5) * DIM + col;

  int slot0 = offs[g] + m0;
  const __hip_bfloat16* Hb = H + (size_t)slot0 * INTERN;

  int srow = tid >> 3, sc8 = tid & 7;
  const __hip_bfloat16* hr = Hb + (size_t)srow * INTERN + sc8 * 16;
  int sswz = (srow & 7) << 4;

  // Wd prefetch depth 4 (static buffers)
  float w0[8], w1[8], w2[8], w3[8];
  ldw8d(w0, bd);
  ldw8d(w1, bd + (size_t)16 * DIM);
  ldw8d(w2, bd + (size_t)32 * DIM);
  ldw8d(w3, bd + (size_t)48 * DIM);

  // stage panel 0
  bf16x8 t0 = *reinterpret_cast<const bf16x8*>(hr);
  bf16x8 t1 = *reinterpret_cast<const bf16x8*>(hr + 8);
  {
    int b0 = srow * 256 + sc8 * 32;
    *reinterpret_cast<bf16x8*>(&hp[0][b0 ^ sswz]) = t0;
    *reinterpret_cast<bf16x8*>(&hp[0][(b0 + 16) ^ sswz]) = t1;
  }
  panel_barrier();

  f32x16 o;
#pragma unroll
  for (int r = 0; r < 16; ++r) o[r] = 0.f;

  int arow = mh * 32 + c31;
  int aswz = (arow & 7) << 4;

#define G2STEP(KSL, WB) { \
    bf16x8 hf = *reinterpret_cast<const bf16x8*>( \
        &hp[pb][(arow * 256 + (KSL) * 32 + h5 * 16) ^ aswz]); \
    o = __builtin_amdgcn_mfma_f32_32x32x16_bf16(hf, cvt8(WB), o, 0, 0, 0); \
    int tn = 8 * p + (KSL) + 4; if (tn > 159) tn = 8 * p + (KSL); \
    ldw8d(WB, bd + (size_t)tn * 16 * DIM); }

  for (int p = 0; p < 20; ++p) {
    int pb = p & 1;
    if (p < 19) {
      t0 = *reinterpret_cast<const bf16x8*>(hr + (p + 1) * 128);
      t1 = *reinterpret_cast<const bf16x8*>(hr + (p + 1) * 128 + 8);
    }
    G2STEP(0, w0) G2STEP(1, w1) G2STEP(2, w2) G2STEP(3, w3)
    G2STEP(4, w0) G2STEP(5, w1) G2STEP(6, w2) G2STEP(7, w3)
    if (p < 19) {
      int b0 = srow * 256 + sc8 * 32;
      *reinterpret_cast<bf16x8*>(&hp[pb ^ 1][b0 ^ sswz]) = t0;
      *reinterpret_cast<bf16x8*>(&hp[pb ^ 1][(b0 + 16) ^ sswz]) = t1;
    }
    panel_barrier();
  }
#undef G2STEP

#pragma unroll
  for (int r = 0; r < 16; ++r) {
    int row = (r & 3) + 8 * (r >> 2) + 4 * h5 + 32 * mh;
    atomicAdd(&out[(size_t)rows_s[row] * DIM + col], o[r] * w_s[row]);
  }
}

// ---------------- fallback: v2 single-kernel ----------------
__global__ __launch_bounds__(512, 2) void moe2_k(
    const float* __restrict__ x, const int* __restrict__ cnt,
    const int* __restrict__ tok, const float* __restrict__ wts,
    const float* __restrict__ Wg, const float* __restrict__ Wu,
    const float* __restrict__ Wd, const float* __restrict__ Sg,
    const float* __restrict__ Su, const float* __restrict__ Sd,
    float* __restrict__ out) {
  int bid = blockIdx.x;
  int g, tile, ch;
  if (bid < 5120) {
    g = (bid & 7) + 8 * ((bid >> 3) & 1);
    tile = (bid >> 4) & 31;
    ch = bid >> 9;
  } else {
    int s = bid - 5120;
    int q = s >> 3;
    ch = q % 10;
    tile = (s & 7) + 8 * (q / 10);
    g = NEXP;
  }
  int M = (g < NEXP) ? cnt[g] : T_TOK;
  int m0 = tile * MT;
  if (m0 >= M) return;

  __shared__ int rows_s[MT];
  __shared__ float w_s[MT];
  __shared__ __align__(16) char xbuf[MT * DIM * 2];
  __shared__ __align__(16) char hbuf[MT * IC * 2];

  int tid = threadIdx.x;
  if (tid < MT) {
    if (g < NEXP) {
      int i = m0 + tid;
      bool v = i < M;
      rows_s[tid] = tok[g * T_TOK + (v ? i : m0)];
      w_s[tid]   = v ? wts[g * T_TOK + i] : 0.f;
    } else {
      rows_s[tid] = m0 + tid;
      w_s[tid]   = 1.f;
    }
  }
  __syncthreads();

  {
    int r = tid >> 3, c8 = tid & 7;
    const float* xr = x + (size_t)rows_s[r] * DIM;
#pragma unroll
    for (int j = 0; j < 28; ++j) {
      int c4 = c8 + 8 * j;
      float4 v = reinterpret_cast<const float4*>(xr)[c4];
      bf16x4 b;
      b[0] = (__bf16)v.x; b[1] = (__bf16)v.y; b[2] = (__bf16)v.z; b[3] = (__bf16)v.w;
      int byte = r * (DIM * 2) + c4 * 8;
      byte ^= (r & 7) << 4;
      *reinterpret_cast<bf16x4*>(xbuf + byte) = b;
    }
  }
  __syncthreads();

  const float* pWg = (g < NEXP) ? Wg + (size_t)g * DIM * INTERN : Sg;
  const float* pWu = (g < NEXP) ? Wu + (size_t)g * DIM * INTERN : Su;
  const float* pWd = (g < NEXP) ? Wd + (size_t)g * INTERN * DIM : Sd;

  int wv = tid >> 6, lane = tid & 63;
  int h5 = lane >> 5, c31 = lane & 31;
  int c0 = ch * IC;

  f32x16 ag0, ag1, au0, au1;
#pragma unroll
  for (int r = 0; r < 16; ++r) { ag0[r] = 0.f; ag1[r] = 0.f; au0[r] = 0.f; au1[r] = 0.f; }

  const float* bg = pWg + (size_t)(8 * h5) * INTERN + c0 + wv * 32 + c31;
  const float* bu = pWu + (size_t)(8 * h5) * INTERN + c0 + wv * 32 + c31;

  float fg0[8], fu0[8], fg1[8], fu1[8];
  ldw8i(fg0, bg); ldw8i(fu0, bu);

#define XFRAG(tokrow, ks) \
  (*reinterpret_cast<const bf16x8*>(xbuf + (((tokrow) * (DIM * 2) + (ks) * 32 + h5 * 16) ^ (((tokrow) & 7) << 4))))

  for (int ks2 = 0; ks2 < 28; ++ks2) {
    int ksA = 2 * ks2, ksB = ksA + 1;
    ldw8i(fg1, bg + (size_t)ksB * 16 * INTERN);
    ldw8i(fu1, bu + (size_t)ksB * 16 * INTERN);
    {
      bf16x8 xa = XFRAG(c31, ksA), xb = XFRAG(c31 + 32, ksA);
      bf16x8 wgf = cvt8(fg0), wuf = cvt8(fu0);
      ag0 = __builtin_amdgcn_mfma_f32_32x32x16_bf16(wgf, xa, ag0, 0, 0, 0);
      ag1 = __builtin_amdgcn_mfma_f32_32x32x16_bf16(wgf, xb, ag1, 0, 0, 0);
      au0 = __builtin_amdgcn_mfma_f32_32x32x16_bf16(wuf, xa, au0, 0, 0, 0);
      au1 = __builtin_amdgcn_mfma_f32_32x32x16_bf16(wuf, xb, au1, 0, 0, 0);
    }
    int ksC = (ks2 < 27) ? (ksA + 2) : 0;
    ldw8i(fg0, bg + (size_t)ksC * 16 * INTERN);
    ldw8i(fu0, bu + (size_t)ksC * 16 * INTERN);
    {
      bf16x8 xa = XFRAG(c31, ksB), xb = XFRAG(c31 + 32, ksB);
      bf16x8 wgf = cvt8(fg1), wuf = cvt8(fu1);
      ag0 = __builtin_amdgcn_mfma_f32_32x32x16_bf16(wgf, xa, ag0, 0, 0, 0);
      ag1 = __builtin_amdgcn_mfma_f32_32x32x16_bf16(wgf, xb, ag1, 0, 0, 0);
      au0 = __builtin_amdgcn_mfma_f32_32x32x16_bf16(wuf, xa, au0, 0, 0, 0);
      au1 = __builtin_amdgcn_mfma_f32_32x32x16_bf16(wuf, xb, au1, 0, 0, 0);
    }
  }

#pragma unroll
  for (int mh = 0; mh < 2; ++mh) {
    int tokr = c31 + 32 * mh;
#pragma unroll
    for (int q = 0; q < 4; ++q) {
      bf16x4 hq;
#pragma unroll
      for (int j = 0; j < 4; ++j) {
        float gg = mh ? ag1[4 * q + j] : ag0[4 * q + j];
        float uu = mh ? au1[4 * q + j] : au0[4 * q + j];
        hq[j] = (__bf16)(gg / (1.f + __expf(-gg)) * uu);
      }
      int i0 = wv * 32 + 8 * q + 4 * h5;
      int byte = tokr * (IC * 2) + i0 * 2;
      byte ^= (tokr & 7) << 4;
      *reinterpret_cast<bf16x4*>(hbuf + byte) = hq;
    }
  }
  __syncthreads();

  int mh = wv & 1;
  int ngb = (wv >> 1) * 7;
  int tokr = c31 + 32 * mh;
  f32x16 o[7];
#pragma unroll
  for (int n = 0; n < 7; ++n)
#pragma unroll
    for (int r = 0; r < 16; ++r) o[n][r] = 0.f;

  const float* bd = pWd + (size_t)(c0 + 8 * h5) * DIM + ngb * 32 + c31;

  float fA[8], fB[8];
#pragma unroll
  for (int e = 0; e < 8; ++e) fA[e] = bd[(size_t)e * DIM];

  auto g2body = [&](int ks, auto P) {
    constexpr int par = decltype(P)::value;
    int hbyte = (tokr * (IC * 2) + ks * 32 + h5 * 16) ^ ((tokr & 7) << 4);
    bf16x8 hf = *reinterpret_cast<const bf16x8*>(hbuf + hbyte);
    const float* bk  = bd + (size_t)(ks * 16) * DIM;
    const float* bk1 = bd + (size_t)(((ks < 15) ? (ks + 1) : ks) * 16) * DIM;
#pragma unroll
    for (int nf = 0; nf < 7; ++nf) {
      float* nxt = (((nf + par) & 1) == 0) ? fB : fA;
      const float* src = (nf < 6) ? (bk + (nf + 1) * 32) : bk1;
#pragma unroll
      for (int e = 0; e < 8; ++e) nxt[e] = src[(size_t)e * DIM];
      const float* cur = (((nf + par) & 1) == 0) ? fA : fB;
      bf16x8 bfr = cvt8(cur);
      o[nf] = __builtin_amdgcn_mfma_f32_32x32x16_bf16(hf, bfr, o[nf], 0, 0, 0);
    }
  };
  for (int k2 = 0; k2 < 8; ++k2) {
    g2body(2 * k2,     std::integral_constant<int, 0>{});
    g2body(2 * k2 + 1, std::integral_constant<int, 1>{});
  }

#pragma unroll
  for (int nf = 0; nf < 7; ++nf) {
    int nc = (ngb + nf) * 32 + c31;
#pragma unroll
    for (int r = 0; r < 16; ++r) {
      int row = (r & 3) + 8 * (r >> 2) + 4 * h5 + 32 * mh;
      atomicAdd(&out[(size_t)rows_s[row] * DIM + nc], o[nf][r] * w_s[row]);
    }
  }
}

extern "C" void kernel_launch(void* const* d_in, const int* in_sizes, int n_in,
                              void* d_out, int out_size, void* d_ws, size_t ws_size,
                              hipStream_t stream) {
  const float* x  = (const float*)d_in[0];
  const float* rw = (const float*)d_in[1];
  const float* Wg = (const float*)d_in[2];
  const float* Wu = (const float*)d_in[3];
  const float* Wd = (const float*)d_in[4];
  const float* Sg = (const float*)d_in[5];
  const float* Su = (const float*)d_in[6];
  const float* Sd = (const float*)d_in[7];
  float* out = (float*)d_out;

  char* ws = (char*)d_ws;
  int*   cnt  = (int*)ws;                         // 0..64
  float* Pacc = (float*)(ws + 64);                // 64..128
  float* facc = (float*)(ws + 128);               // 128..192
  int*   offs = (int*)(ws + 192);                 // 192..320 (17 ints)
  int*   tok  = (int*)(ws + 320);                 // 131072 B
  float* wts  = (float*)(ws + 320 + 131072);      // 131072 B
  const size_t H_OFF = 262656;
  __hip_bfloat16* H = (__hip_bfloat16*)(ws + H_OFF);
  const size_t NEED = H_OFF + (size_t)(2 * T_TOK * TOPK + T_TOK) * INTERN * 2;  // 10240 rows

  hipMemsetAsync(d_ws, 0, 320, stream);
  hipMemsetAsync(d_out, 0, (size_t)(T_TOK * DIM + 1) * sizeof(float), stream);

  router_k<<<T_TOK / 4, 256, 0, stream>>>(x, rw, cnt, Pacc, facc, tok, wts);
  loss_k<<<1, 64, 0, stream>>>(Pacc, facc, cnt, offs, out + (size_t)T_TOK * DIM);

  if (ws_size >= NEED) {
    h_k<<<5440, 512, 0, stream>>>(x, cnt, offs, tok, Wg, Wu, Sg, Su, H);
    g2_k<<<3808, 512, 0, stream>>>(cnt, offs, tok, wts, H, Wd, Sd, out);
  } else {
    moe2_k<<<5440, 512, 0, stream>>>(x, cnt, tok, wts, Wg, Wu, Wd, Sg, Su, Sd, out);
  }
}

// Round 5
// 548.866 us; speedup vs baseline: 6.7150x; 1.2740x over previous
//
#include <hip/hip_runtime.h>
#include <hip/hip_bf16.h>

// HighSparsityMoE v4: weight pre-packing into MFMA-fragment order (bf16).
//  pack_k ×3 : W[k][n] f32 -> P[slot][n_blk][ks][lane][8] bf16 (frag-ordered)
//  h4_k  (g,tile,ch): GEMM1+SwiGLU -> H, W-frags = single coalesced b128 loads
//  g24_k (g,tile,ns): GEMM2 K=2560, Wd-frags = single b128 loads
// Fallback to v3.1 (h_k/g2_k, strided f32 W loads) if ws_size < ~287 MB.

#define T_TOK 2048
#define DIM   896
#define INTERN 2560
#define NEXP  16
#define TOPK  4
#define MT    64
#define IC    256

#define SLOTGU ((size_t)80 * 56 * 512)    // frag elements per GU slot (= 4.59 MB bf16)
#define SLOTD  ((size_t)28 * 160 * 512)   // same count for D

typedef __attribute__((ext_vector_type(8)))  __bf16 bf16x8;
typedef __attribute__((ext_vector_type(4)))  __bf16 bf16x4;
typedef __attribute__((ext_vector_type(16))) float  f32x16;

__device__ __forceinline__ bf16x8 cvt8(const float* f) {
  bf16x8 r;
#pragma unroll
  for (int e = 0; e < 8; ++e) r[e] = (__bf16)f[e];
  return r;
}
__device__ __forceinline__ void ldw8i(float b[8], const float* p) {
#pragma unroll
  for (int e = 0; e < 8; ++e) b[e] = p[(size_t)e * INTERN];
}
__device__ __forceinline__ void ldw8d(float b[8], const float* p) {
#pragma unroll
  for (int e = 0; e < 8; ++e) b[e] = p[(size_t)e * DIM];
}
// barrier that does NOT drain vmcnt (keeps global prefetch in flight)
__device__ __forceinline__ void panel_barrier() {
  asm volatile("s_waitcnt lgkmcnt(0)" ::: "memory");
  __builtin_amdgcn_s_barrier();
  __builtin_amdgcn_sched_barrier(0);
}

// ---------------- K1: router ----------------
__global__ void router_k(const float* __restrict__ x, const float* __restrict__ rw,
                         int* __restrict__ cnt, float* __restrict__ Pacc,
                         float* __restrict__ facc, int* __restrict__ tok,
                         float* __restrict__ wts) {
  int lane = threadIdx.x & 63;
  int t = blockIdx.x * 4 + (threadIdx.x >> 6);
  const float* xr = x + (size_t)t * DIM;

  float acc[NEXP];
#pragma unroll
  for (int e = 0; e < NEXP; ++e) acc[e] = 0.f;
  for (int i = 0; i < DIM / 64; ++i) {
    int d = i * 64 + lane;
    float xv = xr[d];
    const float* r = rw + d * NEXP;
#pragma unroll
    for (int e = 0; e < NEXP; ++e) acc[e] = fmaf(xv, r[e], acc[e]);
  }
#pragma unroll
  for (int e = 0; e < NEXP; ++e) {
    float v = acc[e];
    v += __shfl_xor(v, 32); v += __shfl_xor(v, 16); v += __shfl_xor(v, 8);
    v += __shfl_xor(v, 4);  v += __shfl_xor(v, 2);  v += __shfl_xor(v, 1);
    acc[e] = v;
  }
  float m = acc[0];
#pragma unroll
  for (int e = 1; e < NEXP; ++e) m = fmaxf(m, acc[e]);
  float p[NEXP]; float s = 0.f;
#pragma unroll
  for (int e = 0; e < NEXP; ++e) { p[e] = __expf(acc[e] - m); s += p[e]; }
  float is = 1.f / s;
#pragma unroll
  for (int e = 0; e < NEXP; ++e) p[e] *= is;

  float pc[NEXP];
#pragma unroll
  for (int e = 0; e < NEXP; ++e) pc[e] = p[e];
  int sels[TOPK]; float svs[TOPK]; float s4 = 0.f;
#pragma unroll
  for (int k = 0; k < TOPK; ++k) {
    int best = 0; float bv = pc[0];
#pragma unroll
    for (int e = 1; e < NEXP; ++e) { if (pc[e] > bv) { bv = pc[e]; best = e; } }
    sels[k] = best; svs[k] = bv; s4 += bv;
#pragma unroll
    for (int e = 0; e < NEXP; ++e) { if (e == best) pc[e] = -1.f; }
  }
  float inv = 1.f / (s4 + 1e-8f);

  if (lane < NEXP) atomicAdd(&Pacc[lane], p[lane] * (1.f / T_TOK));
  if (lane < TOPK) {
    int e = sels[lane]; float w = svs[lane] * inv;
    atomicAdd(&facc[e], 1.f / T_TOK);
    int pos = atomicAdd(&cnt[e], 1);
    tok[e * T_TOK + pos] = t;
    wts[e * T_TOK + pos] = w;
  }
}

// ---------------- K2: balance loss + expert offsets ----------------
__global__ void loss_k(const float* __restrict__ Pacc, const float* __restrict__ facc,
                       const int* __restrict__ cnt, int* __restrict__ offs,
                       float* __restrict__ dst) {
  if (threadIdx.x == 0) {
    float s = 0.f;
    for (int e = 0; e < NEXP; ++e) s += Pacc[e] * facc[e];
    *dst = (float)NEXP * s;
    int o = 0;
    for (int e = 0; e < NEXP; ++e) { offs[e] = o; o += cnt[e]; }
    offs[NEXP] = o;
  }
}

// ---------------- K0: pack weights into frag order ----------------
// src [K][N] f32 (N contig). dst chunk (n_blk,ks): 64 lanes x 8 bf16,
// element = src[16*ks + 8*(lane>>5) + e][32*n_blk + (lane&31)].
__global__ __launch_bounds__(256, 8) void pack_k(
    const float* __restrict__ srcE, const float* __restrict__ srcS,
    __hip_bfloat16* __restrict__ dst, int K, int N) {
  int kt = blockIdx.x, nt = blockIdx.y, z = blockIdx.z;
  const float* src = (z < NEXP) ? srcE + (size_t)z * K * N : srcS;
  __hip_bfloat16* d = dst + (size_t)z * ((size_t)(K >> 4) * (N >> 5) * 512);
  __shared__ float tile[64][65];
  int tid = threadIdx.x;
  int r0 = tid >> 4, c4 = (tid & 15) << 2;
  const float* s = src + (size_t)(kt * 64) * N + nt * 64;
#pragma unroll
  for (int it = 0; it < 4; ++it) {
    int r = r0 + 16 * it;
    float4 v = *reinterpret_cast<const float4*>(s + (size_t)r * N + c4);
    tile[r][c4] = v.x; tile[r][c4 + 1] = v.y;
    tile[r][c4 + 2] = v.z; tile[r][c4 + 3] = v.w;
  }
  __syncthreads();
  int lane = tid & 63, h5 = lane >> 5, c31 = lane & 31;
  int KS = K >> 4;
#pragma unroll
  for (int it = 0; it < 2; ++it) {
    int cc = (tid >> 6) + 4 * it;          // 0..7: 2 n_blk x 4 ks
    int nbl = cc >> 2, ksl = cc & 3;
    bf16x8 v;
#pragma unroll
    for (int e = 0; e < 8; ++e)
      v[e] = (__bf16)tile[ksl * 16 + 8 * h5 + e][nbl * 32 + c31];
    size_t n_blk = (size_t)nt * 2 + nbl, ks = (size_t)kt * 4 + ksl;
    *reinterpret_cast<bf16x8*>(d + ((n_blk * KS + ks) * 64 + lane) * 8) = v;
  }
}

// ---------------- K3a v4: h4_k — GEMM1 + SwiGLU -> H (packed W) ----------------
__global__ __launch_bounds__(512, 4) void h4_k(
    const float* __restrict__ x, const int* __restrict__ cnt,
    const int* __restrict__ offs, const int* __restrict__ tok,
    const __hip_bfloat16* __restrict__ PG, const __hip_bfloat16* __restrict__ PU,
    __hip_bfloat16* __restrict__ H) {
  int bid = blockIdx.x;
  int g, tile, ch;
  if (bid < 5120) {                      // routed: bid%8 == g&7 (XCD affinity)
    g = (bid & 7) + 8 * ((bid >> 3) & 1);
    tile = (bid >> 4) & 31;
    ch = bid >> 9;
  } else {
    int s = bid - 5120;
    tile = s & 31;
    ch = s >> 5;
    g = NEXP;
  }
  int M = (g < NEXP) ? cnt[g] : T_TOK;
  int m0 = tile * MT;
  if (m0 >= M) return;

  __shared__ int rows_s[MT];
  __shared__ __align__(16) char xph[32768];     // 2 x-panels; reused as hb at end
  char (*xp)[16384] = reinterpret_cast<char (*)[16384]>(xph);
  char* hb = xph;

  int tid = threadIdx.x;
  if (tid < MT) {
    if (g < NEXP) {
      int i = m0 + tid;
      rows_s[tid] = tok[g * T_TOK + ((i < M) ? i : m0)];
    } else rows_s[tid] = m0 + tid;
  }
  __syncthreads();

  int wv = tid >> 6, lane = tid & 63;
  int h5 = lane >> 5, c31 = lane & 31;

  int srow = tid >> 3, sc8 = tid & 7;
  const float* xr = x + (size_t)rows_s[srow] * DIM;
  int sswz = (srow & 7) << 4;

#define LDX(p, j) (*reinterpret_cast<const float4*>(xr + (p) * 128 + (sc8 + 8 * (j)) * 4))
#define STX(pb, j, v) { bf16x4 _b; _b[0]=(__bf16)(v).x; _b[1]=(__bf16)(v).y; \
    _b[2]=(__bf16)(v).z; _b[3]=(__bf16)(v).w; \
    *reinterpret_cast<bf16x4*>(&xp[pb][(srow * 256 + sc8 * 8 + 64 * (j)) ^ sswz]) = _b; }
#define XF(pb, row, ksl) (*reinterpret_cast<const bf16x8*>( \
    &xp[pb][((row) * 256 + (ksl) * 32 + h5 * 16) ^ (((row) & 7) << 4)]))

  int slot = (g < NEXP) ? g : NEXP;
  const __hip_bfloat16* bg = PG + (size_t)slot * SLOTGU +
      ((size_t)(ch * 8 + wv) * 56) * 512 + lane * 8;
  const __hip_bfloat16* bu = PU + (size_t)slot * SLOTGU +
      ((size_t)(ch * 8 + wv) * 56) * 512 + lane * 8;

  bf16x8 wg0 = *reinterpret_cast<const bf16x8*>(bg);
  bf16x8 wu0 = *reinterpret_cast<const bf16x8*>(bu);
  bf16x8 wg1, wu1;

  // prologue: stage x-panel 0
  {
    float4 a0 = LDX(0, 0), a1 = LDX(0, 1), a2 = LDX(0, 2), a3 = LDX(0, 3);
    STX(0, 0, a0) STX(0, 1, a1) STX(0, 2, a2) STX(0, 3, a3)
  }
  panel_barrier();

  f32x16 ag0, ag1, au0, au1;
#pragma unroll
  for (int r = 0; r < 16; ++r) { ag0[r] = 0.f; ag1[r] = 0.f; au0[r] = 0.f; au1[r] = 0.f; }

  float4 s0, s1, s2, s3;
  for (int p = 0; p < 7; ++p) {
    int pb = p & 1;
    if (p < 6) { s0 = LDX(p + 1, 0); s1 = LDX(p + 1, 1); }
#pragma unroll
    for (int q = 0; q < 4; ++q) {
      int ksB = 8 * p + 2 * q + 1;
      wg1 = *reinterpret_cast<const bf16x8*>(bg + (size_t)ksB * 512);
      wu1 = *reinterpret_cast<const bf16x8*>(bu + (size_t)ksB * 512);
      {
        bf16x8 xa = XF(pb, c31, 2 * q), xb = XF(pb, c31 + 32, 2 * q);
        ag0 = __builtin_amdgcn_mfma_f32_32x32x16_bf16(wg0, xa, ag0, 0, 0, 0);
        ag1 = __builtin_amdgcn_mfma_f32_32x32x16_bf16(wg0, xb, ag1, 0, 0, 0);
        au0 = __builtin_amdgcn_mfma_f32_32x32x16_bf16(wu0, xa, au0, 0, 0, 0);
        au1 = __builtin_amdgcn_mfma_f32_32x32x16_bf16(wu0, xb, au1, 0, 0, 0);
      }
      int ksC = (8 * p + 2 * q + 2 < 56) ? (8 * p + 2 * q + 2) : 0;
      wg0 = *reinterpret_cast<const bf16x8*>(bg + (size_t)ksC * 512);
      wu0 = *reinterpret_cast<const bf16x8*>(bu + (size_t)ksC * 512);
      {
        bf16x8 xa = XF(pb, c31, 2 * q + 1), xb = XF(pb, c31 + 32, 2 * q + 1);
        ag0 = __builtin_amdgcn_mfma_f32_32x32x16_bf16(wg1, xa, ag0, 0, 0, 0);
        ag1 = __builtin_amdgcn_mfma_f32_32x32x16_bf16(wg1, xb, ag1, 0, 0, 0);
        au0 = __builtin_amdgcn_mfma_f32_32x32x16_bf16(wu1, xa, au0, 0, 0, 0);
        au1 = __builtin_amdgcn_mfma_f32_32x32x16_bf16(wu1, xb, au1, 0, 0, 0);
      }
      if (q == 1 && p < 6) {
        STX(pb ^ 1, 0, s0) STX(pb ^ 1, 1, s1)
        s2 = LDX(p + 1, 2); s3 = LDX(p + 1, 3);
      }
    }
    if (p < 6) { STX(pb ^ 1, 2, s2) STX(pb ^ 1, 3, s3) }
    panel_barrier();
  }

  // SwiGLU in-register -> hb ([tok][256] bf16, swizzled); hb aliases xp (safe:
  // last panel's reads completed before the final panel_barrier above).
#pragma unroll
  for (int mh = 0; mh < 2; ++mh) {
    int tokr = c31 + 32 * mh;
#pragma unroll
    for (int q = 0; q < 4; ++q) {
      bf16x4 hq;
#pragma unroll
      for (int j = 0; j < 4; ++j) {
        float gg = mh ? ag1[4 * q + j] : ag0[4 * q + j];
        float uu = mh ? au1[4 * q + j] : au0[4 * q + j];
        hq[j] = (__bf16)(gg / (1.f + __expf(-gg)) * uu);
      }
      int i0 = wv * 32 + 8 * q + 4 * h5;
      int byte = (tokr * 512 + i0 * 2) ^ ((tokr & 7) << 4);
      *reinterpret_cast<bf16x4*>(&hb[byte]) = hq;
    }
  }
  panel_barrier();

  // wide store hb -> H[slot][c0..c0+256), valid rows only (tail-tile fix)
  if (g == NEXP || m0 + srow < M) {
    int slotr = offs[g] + m0 + srow;
    __hip_bfloat16* hrow = H + (size_t)slotr * INTERN + ch * IC + sc8 * 32;
#pragma unroll
    for (int qq = 0; qq < 4; ++qq) {
      int byte = (srow * 512 + sc8 * 64 + qq * 16) ^ sswz;
      *reinterpret_cast<bf16x8*>(hrow + qq * 8) =
          *reinterpret_cast<const bf16x8*>(&hb[byte]);
    }
  }
#undef LDX
#undef STX
#undef XF
}

// ---------------- K3b v4: g24_k — O = H @ Wd (packed Wd) ----------------
__global__ __launch_bounds__(512, 4) void g24_k(
    const int* __restrict__ cnt, const int* __restrict__ offs,
    const int* __restrict__ tok, const float* __restrict__ wts,
    const __hip_bfloat16* __restrict__ H,
    const __hip_bfloat16* __restrict__ PD, float* __restrict__ out) {
  int bid = blockIdx.x;
  int g, tile, ns;
  if (bid < 3584) {
    g = (bid & 7) + 8 * ((bid >> 3) & 1);
    tile = (bid >> 4) & 31;
    ns = bid >> 9;                       // 0..6
  } else {
    int s = bid - 3584;
    tile = s & 31;
    ns = s >> 5;
    g = NEXP;
  }
  int M = (g < NEXP) ? cnt[g] : T_TOK;
  int m0 = tile * MT;
  if (m0 >= M) return;

  __shared__ int rows_s[MT];
  __shared__ float w_s[MT];
  __shared__ __align__(16) char hp[2][16384];

  int tid = threadIdx.x;
  if (tid < MT) {
    if (g < NEXP) {
      int i = m0 + tid; bool v = i < M;
      rows_s[tid] = tok[g * T_TOK + (v ? i : m0)];
      w_s[tid]   = v ? wts[g * T_TOK + i] : 0.f;
    } else { rows_s[tid] = m0 + tid; w_s[tid] = 1.f; }
  }
  __syncthreads();

  int wv = tid >> 6, lane = tid & 63, h5 = lane >> 5, c31 = lane & 31;
  int mh = wv & 1, ng = wv >> 1;
  int col = ns * 128 + ng * 32 + c31;

  int slot = (g < NEXP) ? g : NEXP;
  const __hip_bfloat16* bd = PD + (size_t)slot * SLOTD +
      ((size_t)(ns * 4 + ng) * 160) * 512 + lane * 8;

  int slot0 = offs[g] + m0;
  const __hip_bfloat16* Hb = H + (size_t)slot0 * INTERN;

  int srow = tid >> 3, sc8 = tid & 7;
  const __hip_bfloat16* hr = Hb + (size_t)srow * INTERN + sc8 * 16;
  int sswz = (srow & 7) << 4;

  // Wd frag prefetch depth 4
  bf16x8 w0 = *reinterpret_cast<const bf16x8*>(bd);
  bf16x8 w1 = *reinterpret_cast<const bf16x8*>(bd + 512);
  bf16x8 w2 = *reinterpret_cast<const bf16x8*>(bd + 1024);
  bf16x8 w3 = *reinterpret_cast<const bf16x8*>(bd + 1536);

  // stage H panel 0
  bf16x8 t0 = *reinterpret_cast<const bf16x8*>(hr);
  bf16x8 t1 = *reinterpret_cast<const bf16x8*>(hr + 8);
  {
    int b0 = srow * 256 + sc8 * 32;
    *reinterpret_cast<bf16x8*>(&hp[0][b0 ^ sswz]) = t0;
    *reinterpret_cast<bf16x8*>(&hp[0][(b0 + 16) ^ sswz]) = t1;
  }
  panel_barrier();

  f32x16 o;
#pragma unroll
  for (int r = 0; r < 16; ++r) o[r] = 0.f;

  int arow = mh * 32 + c31;
  int aswz = (arow & 7) << 4;

#define G2STEP(KSL, WB) { \
    bf16x8 hf = *reinterpret_cast<const bf16x8*>( \
        &hp[pb][(arow * 256 + (KSL) * 32 + h5 * 16) ^ aswz]); \
    o = __builtin_amdgcn_mfma_f32_32x32x16_bf16(hf, WB, o, 0, 0, 0); \
    int tn = 8 * p + (KSL) + 4; if (tn > 159) tn = 8 * p + (KSL); \
    WB = *reinterpret_cast<const bf16x8*>(bd + (size_t)tn * 512); }

  for (int p = 0; p < 20; ++p) {
    int pb = p & 1;
    if (p < 19) {
      t0 = *reinterpret_cast<const bf16x8*>(hr + (p + 1) * 128);
      t1 = *reinterpret_cast<const bf16x8*>(hr + (p + 1) * 128 + 8);
    }
    G2STEP(0, w0) G2STEP(1, w1) G2STEP(2, w2) G2STEP(3, w3)
    G2STEP(4, w0) G2STEP(5, w1) G2STEP(6, w2) G2STEP(7, w3)
    if (p < 19) {
      int b0 = srow * 256 + sc8 * 32;
      *reinterpret_cast<bf16x8*>(&hp[pb ^ 1][b0 ^ sswz]) = t0;
      *reinterpret_cast<bf16x8*>(&hp[pb ^ 1][(b0 + 16) ^ sswz]) = t1;
    }
    panel_barrier();
  }
#undef G2STEP

#pragma unroll
  for (int r = 0; r < 16; ++r) {
    int row = (r & 3) + 8 * (r >> 2) + 4 * h5 + 32 * mh;
    atomicAdd(&out[(size_t)rows_s[row] * DIM + col], o[r] * w_s[row]);
  }
}

// ---------------- v3.1 fallback: h_k (strided f32 W loads) ----------------
__global__ __launch_bounds__(512, 4) void h_k(
    const float* __restrict__ x, const int* __restrict__ cnt,
    const int* __restrict__ offs, const int* __restrict__ tok,
    const float* __restrict__ Wg, const float* __restrict__ Wu,
    const float* __restrict__ Sg, const float* __restrict__ Su,
    __hip_bfloat16* __restrict__ H) {
  int bid = blockIdx.x;
  int g, tile, ch;
  if (bid < 5120) {
    g = (bid & 7) + 8 * ((bid >> 3) & 1);
    tile = (bid >> 4) & 31;
    ch = bid >> 9;
  } else {
    int s = bid - 5120;
    tile = s & 31;
    ch = s >> 5;
    g = NEXP;
  }
  int M = (g < NEXP) ? cnt[g] : T_TOK;
  int m0 = tile * MT;
  if (m0 >= M) return;

  __shared__ int rows_s[MT];
  __shared__ __align__(16) char xp[2][16384];
  __shared__ __align__(16) char hb[MT * IC * 2];

  int tid = threadIdx.x;
  if (tid < MT) {
    if (g < NEXP) {
      int i = m0 + tid;
      rows_s[tid] = tok[g * T_TOK + ((i < M) ? i : m0)];
    } else rows_s[tid] = m0 + tid;
  }
  __syncthreads();

  const float* pWg = (g < NEXP) ? Wg + (size_t)g * DIM * INTERN : Sg;
  const float* pWu = (g < NEXP) ? Wu + (size_t)g * DIM * INTERN : Su;

  int wv = tid >> 6, lane = tid & 63;
  int h5 = lane >> 5, c31 = lane & 31;
  int c0 = ch * IC;

  int srow = tid >> 3, sc8 = tid & 7;
  const float* xr = x + (size_t)rows_s[srow] * DIM;
  int sswz = (srow & 7) << 4;

#define LDX(p, j) (*reinterpret_cast<const float4*>(xr + (p) * 128 + (sc8 + 8 * (j)) * 4))
#define STX(pb, j, v) { bf16x4 _b; _b[0]=(__bf16)(v).x; _b[1]=(__bf16)(v).y; \
    _b[2]=(__bf16)(v).z; _b[3]=(__bf16)(v).w; \
    *reinterpret_cast<bf16x4*>(&xp[pb][(srow * 256 + sc8 * 8 + 64 * (j)) ^ sswz]) = _b; }
#define XF(pb, row, ksl) (*reinterpret_cast<const bf16x8*>( \
    &xp[pb][((row) * 256 + (ksl) * 32 + h5 * 16) ^ (((row) & 7) << 4)]))

  const float* bg = pWg + (size_t)(8 * h5) * INTERN + c0 + wv * 32 + c31;
  const float* bu = pWu + (size_t)(8 * h5) * INTERN + c0 + wv * 32 + c31;

  float fg0[8], fu0[8], fg1[8], fu1[8];
  ldw8i(fg0, bg); ldw8i(fu0, bu);

  {
    float4 a0 = LDX(0, 0), a1 = LDX(0, 1), a2 = LDX(0, 2), a3 = LDX(0, 3);
    STX(0, 0, a0) STX(0, 1, a1) STX(0, 2, a2) STX(0, 3, a3)
  }
  panel_barrier();

  f32x16 ag0, ag1, au0, au1;
#pragma unroll
  for (int r = 0; r < 16; ++r) { ag0[r] = 0.f; ag1[r] = 0.f; au0[r] = 0.f; au1[r] = 0.f; }

  float4 s0, s1, s2, s3;
  for (int p = 0; p < 7; ++p) {
    int pb = p & 1;
    if (p < 6) { s0 = LDX(p + 1, 0); s1 = LDX(p + 1, 1); }
#pragma unroll
    for (int q = 0; q < 4; ++q) {
      int ksB = 8 * p + 2 * q + 1;
      ldw8i(fg1, bg + (size_t)ksB * 16 * INTERN);
      ldw8i(fu1, bu + (size_t)ksB * 16 * INTERN);
      {
        bf16x8 xa = XF(pb, c31, 2 * q), xb = XF(pb, c31 + 32, 2 * q);
        bf16x8 wgf = cvt8(fg0), wuf = cvt8(fu0);
        ag0 = __builtin_amdgcn_mfma_f32_32x32x16_bf16(wgf, xa, ag0, 0, 0, 0);
        ag1 = __builtin_amdgcn_mfma_f32_32x32x16_bf16(wgf, xb, ag1, 0, 0, 0);
        au0 = __builtin_amdgcn_mfma_f32_32x32x16_bf16(wuf, xa, au0, 0, 0, 0);
        au1 = __builtin_amdgcn_mfma_f32_32x32x16_bf16(wuf, xb, au1, 0, 0, 0);
      }
      int ksC = (8 * p + 2 * q + 2 < 56) ? (8 * p + 2 * q + 2) : 0;
      ldw8i(fg0, bg + (size_t)ksC * 16 * INTERN);
      ldw8i(fu0, bu + (size_t)ksC * 16 * INTERN);
      {
        bf16x8 xa = XF(pb, c31, 2 * q + 1), xb = XF(pb, c31 + 32, 2 * q + 1);
        bf16x8 wgf = cvt8(fg1), wuf = cvt8(fu1);
        ag0 = __builtin_amdgcn_mfma_f32_32x32x16_bf16(wgf, xa, ag0, 0, 0, 0);
        ag1 = __builtin_amdgcn_mfma_f32_32x32x16_bf16(wgf, xb, ag1, 0, 0, 0);
        au0 = __builtin_amdgcn_mfma_f32_32x32x16_bf16(wuf, xa, au0, 0, 0, 0);
        au1 = __builtin_amdgcn_mfma_f32_32x32x16_bf16(wuf, xb, au1, 0, 0, 0);
      }
      if (q == 1 && p < 6) {
        STX(pb ^ 1, 0, s0) STX(pb ^ 1, 1, s1)
        s2 = LDX(p + 1, 2); s3 = LDX(p + 1, 3);
      }
    }
    if (p < 6) { STX(pb ^ 1, 2, s2) STX(pb ^ 1, 3, s3) }
    panel_barrier();
  }

#pragma unroll
  for (int mh = 0; mh < 2; ++mh) {
    int tokr = c31 + 32 * mh;
#pragma unroll
    for (int q = 0; q < 4; ++q) {
      bf16x4 hq;
#pragma unroll
      for (int j = 0; j < 4; ++j) {
        float gg = mh ? ag1[4 * q + j] : ag0[4 * q + j];
        float uu = mh ? au1[4 * q + j] : au0[4 * q + j];
        hq[j] = (__bf16)(gg / (1.f + __expf(-gg)) * uu);
      }
      int i0 = wv * 32 + 8 * q + 4 * h5;
      int byte = (tokr * 512 + i0 * 2) ^ ((tokr & 7) << 4);
      *reinterpret_cast<bf16x4*>(&hb[byte]) = hq;
    }
  }
  panel_barrier();

  if (g == NEXP || m0 + srow < M) {
    int slot = offs[g] + m0 + srow;
    __hip_bfloat16* hrow = H + (size_t)slot * INTERN + c0 + sc8 * 32;
#pragma unroll
    for (int qq = 0; qq < 4; ++qq) {
      int byte = (srow * 512 + sc8 * 64 + qq * 16) ^ sswz;
      *reinterpret_cast<bf16x8*>(hrow + qq * 8) =
          *reinterpret_cast<const bf16x8*>(&hb[byte]);
    }
  }
#undef LDX
#undef STX
#undef XF
}

// ---------------- v3.1 fallback: g2_k ----------------
__global__ __launch_bounds__(512, 4) void g2_k(
    const int* __restrict__ cnt, const int* __restrict__ offs,
    const int* __restrict__ tok, const float* __restrict__ wts,
    const __hip_bfloat16* __restrict__ H,
    const float* __restrict__ Wd, const float* __restrict__ Sd,
    float* __restrict__ out) {
  int bid = blockIdx.x;
  int g, tile, ns;
  if (bid < 3584) {
    g = (bid & 7) + 8 * ((bid >> 3) & 1);
    tile = (bid >> 4) & 31;
    ns = bid >> 9;
  } else {
    int s = bid - 3584;
    tile = s & 31;
    ns = s >> 5;
    g = NEXP;
  }
  int M = (g < NEXP) ? cnt[g] : T_TOK;
  int m0 = tile * MT;
  if (m0 >= M) return;

  __shared__ int rows_s[MT];
  __shared__ float w_s[MT];
  __shared__ __align__(16) char hp[2][16384];

  int tid = threadIdx.x;
  if (tid < MT) {
    if (g < NEXP) {
      int i = m0 + tid; bool v = i < M;
      rows_s[tid] = tok[g * T_TOK + (v ? i : m0)];
      w_s[tid]   = v ? wts[g * T_TOK + i] : 0.f;
    } else { rows_s[tid] = m0 + tid; w_s[tid] = 1.f; }
  }
  __syncthreads();

  const float* pWd = (g < NEXP) ? Wd + (size_t)g * INTERN * DIM : Sd;
  int wv = tid >> 6, lane = tid & 63, h5 = lane >> 5, c31 = lane & 31;
  int mh = wv & 1, ng = wv >> 1;
  int col = ns * 128 + ng * 32 + c31;
  const float* bd = pWd + (size_t)(8 * h5) * DIM + col;

  int slot0 = offs[g] + m0;
  const __hip_bfloat16* Hb = H + (size_t)slot0 * INTERN;

  int srow = tid >> 3, sc8 = tid & 7;
  const __hip_bfloat16* hr = Hb + (size_t)srow * INTERN + sc8 * 16;
  int sswz = (srow & 7) << 4;

  float w0[8], w1[8], w2[8], w3[8];
  ldw8d(w0, bd);
  ldw8d(w1, bd + (size_t)16 * DIM);
  ldw8d(w2, bd + (size_t)32 * DIM);
  ldw8d(w3, bd + (size_t)48 * DIM);

  bf16x8 t0 = *reinterpret_cast<const bf16x8*>(hr);
  bf16x8 t1 = *reinterpret_cast<const bf16x8*>(hr + 8);
  {
    int b0 = srow * 256 + sc8 * 32;
    *reinterpret_cast<bf16x8*>(&hp[0][b0 ^ sswz]) = t0;
    *reinterpret_cast<bf16x8*>(&hp[0][(b0 + 16) ^ sswz]) = t1;
  }
  panel_barrier();

  f32x16 o;
#pragma unroll
  for (int r = 0; r < 16; ++r) o[r] = 0.f;

  int arow = mh * 32 + c31;
  int aswz = (arow & 7) << 4;

#define G2STEP(KSL, WB) { \
    bf16x8 hf = *reinterpret_cast<const bf16x8*>( \
        &hp[pb][(arow * 256 + (KSL) * 32 + h5 * 16) ^ aswz]); \
    o = __builtin_amdgcn_mfma_f32_32x32x16_bf16(hf, cvt8(WB), o, 0, 0, 0); \
    int tn = 8 * p + (KSL) + 4; if (tn > 159) tn = 8 * p + (KSL); \
    ldw8d(WB, bd + (size_t)tn * 16 * DIM); }

  for (int p = 0; p < 20; ++p) {
    int pb = p & 1;
    if (p < 19) {
      t0 = *reinterpret_cast<const bf16x8*>(hr + (p + 1) * 128);
      t1 = *reinterpret_cast<const bf16x8*>(hr + (p + 1) * 128 + 8);
    }
    G2STEP(0, w0) G2STEP(1, w1) G2STEP(2, w2) G2STEP(3, w3)
    G2STEP(4, w0) G2STEP(5, w1) G2STEP(6, w2) G2STEP(7, w3)
    if (p < 19) {
      int b0 = srow * 256 + sc8 * 32;
      *reinterpret_cast<bf16x8*>(&hp[pb ^ 1][b0 ^ sswz]) = t0;
      *reinterpret_cast<bf16x8*>(&hp[pb ^ 1][(b0 + 16) ^ sswz]) = t1;
    }
    panel_barrier();
  }
#undef G2STEP

#pragma unroll
  for (int r = 0; r < 16; ++r) {
    int row = (r & 3) + 8 * (r >> 2) + 4 * h5 + 32 * mh;
    atomicAdd(&out[(size_t)rows_s[row] * DIM + col], o[r] * w_s[row]);
  }
}

extern "C" void kernel_launch(void* const* d_in, const int* in_sizes, int n_in,
                              void* d_out, int out_size, void* d_ws, size_t ws_size,
                              hipStream_t stream) {
  const float* x  = (const float*)d_in[0];
  const float* rw = (const float*)d_in[1];
  const float* Wg = (const float*)d_in[2];
  const float* Wu = (const float*)d_in[3];
  const float* Wd = (const float*)d_in[4];
  const float* Sg = (const float*)d_in[5];
  const float* Su = (const float*)d_in[6];
  const float* Sd = (const float*)d_in[7];
  float* out = (float*)d_out;

  char* ws = (char*)d_ws;
  int*   cnt  = (int*)ws;
  float* Pacc = (float*)(ws + 64);
  float* facc = (float*)(ws + 128);
  int*   offs = (int*)(ws + 192);
  int*   tok  = (int*)(ws + 320);
  float* wts  = (float*)(ws + 320 + 131072);
  const size_t H_OFF = 262656;
  __hip_bfloat16* H = (__hip_bfloat16*)(ws + H_OFF);
  const size_t H_BYTES = (size_t)(2 * T_TOK * TOPK + T_TOK) * INTERN * 2;  // 10240 rows
  const size_t NEED_V3 = H_OFF + H_BYTES;

  const size_t PG_OFF = H_OFF + H_BYTES;            // 52,691,456
  const size_t PBYTES = (size_t)17 * SLOTGU * 2;    // 77,987,840
  const size_t PU_OFF = PG_OFF + PBYTES;
  const size_t PD_OFF = PU_OFF + PBYTES;
  const size_t NEED_V4 = PD_OFF + (size_t)17 * SLOTD * 2;  // ~287 MB
  __hip_bfloat16* PG = (__hip_bfloat16*)(ws + PG_OFF);
  __hip_bfloat16* PU = (__hip_bfloat16*)(ws + PU_OFF);
  __hip_bfloat16* PD = (__hip_bfloat16*)(ws + PD_OFF);

  hipMemsetAsync(d_ws, 0, 320, stream);
  hipMemsetAsync(d_out, 0, (size_t)(T_TOK * DIM + 1) * sizeof(float), stream);

  router_k<<<T_TOK / 4, 256, 0, stream>>>(x, rw, cnt, Pacc, facc, tok, wts);
  loss_k<<<1, 64, 0, stream>>>(Pacc, facc, cnt, offs, out + (size_t)T_TOK * DIM);

  if (ws_size >= NEED_V4) {
    dim3 gGU(DIM / 64, INTERN / 64, NEXP + 1);   // (14,40,17)
    dim3 gD(INTERN / 64, DIM / 64, NEXP + 1);    // (40,14,17)
    pack_k<<<gGU, 256, 0, stream>>>(Wg, Sg, PG, DIM, INTERN);
    pack_k<<<gGU, 256, 0, stream>>>(Wu, Su, PU, DIM, INTERN);
    pack_k<<<gD, 256, 0, stream>>>(Wd, Sd, PD, INTERN, DIM);
    h4_k<<<5440, 512, 0, stream>>>(x, cnt, offs, tok, PG, PU, H);
    g24_k<<<3808, 512, 0, stream>>>(cnt, offs, tok, wts, H, PD, out);
  } else if (ws_size >= NEED_V3) {
    h_k<<<5440, 512, 0, stream>>>(x, cnt, offs, tok, Wg, Wu, Sg, Su, H);
    g2_k<<<3808, 512, 0, stream>>>(cnt, offs, tok, wts, H, Wd, Sd, out);
  }
}